// Round 4
// baseline (745.450 us; speedup 1.0000x reference)
//
#include <hip/hip_runtime.h>
#include <hip/hip_bf16.h>

#define NE   8
#define DIN  2048
#define DOUT 8192
#define NTOK 8192

typedef __bf16 bf16;
typedef __attribute__((ext_vector_type(8))) __bf16 bf16x8;
typedef __attribute__((ext_vector_type(4))) float f32x4;

// round-to-nearest-even f32 -> bf16 (finite inputs)
__device__ __forceinline__ bf16 f2bf(float x) {
  union { float f; unsigned u; } v; v.f = x;
  unsigned r = v.u + 0x7fffu + ((v.u >> 16) & 1u);
  union { unsigned short s; bf16 b; } o; o.s = (unsigned short)(r >> 16);
  return o.b;
}

// ---------------- pass 1a: A fp32 -> bf16 (same layout) ----------------
__global__ __launch_bounds__(256) void convertA(const float* __restrict__ A,
                                                bf16* __restrict__ Ab) {
  size_t i = ((size_t)blockIdx.x * 256 + threadIdx.x) * 8;
  float4 a = *(const float4*)(A + i);
  float4 b = *(const float4*)(A + i + 4);
  const float* f = (const float*)&a;
  const float* g = (const float*)&b;
  bf16x8 v;
  #pragma unroll
  for (int j = 0; j < 4; ++j) { v[j] = f2bf(f[j]); v[4 + j] = f2bf(g[j]); }
  *(bf16x8*)(Ab + i) = v;
}

// ------- pass 1b: W [E][K][N] fp32 -> BT [E][N][K] bf16 (transpose) -------
__global__ __launch_bounds__(256) void convertB(const float* __restrict__ W,
                                                bf16* __restrict__ BT) {
  __shared__ bf16 tile[64][66];
  const int e  = blockIdx.z;
  const int n0 = blockIdx.x * 64;
  const int k0 = blockIdx.y * 64;
  const int t  = threadIdx.x;
  const int tr = t >> 2;
  const int tc = (t & 3) << 4;

  const float* src = W + ((size_t)e * DIN + k0 + tr) * DOUT + n0 + tc;
  #pragma unroll
  for (int i = 0; i < 4; ++i) {
    float4 v = *(const float4*)(src + 4 * i);
    const float* f = (const float*)&v;
    #pragma unroll
    for (int j = 0; j < 4; ++j) tile[tr][tc + 4 * i + j] = f2bf(f[j]);
  }
  __syncthreads();

  bf16x8 v0, v1;
  #pragma unroll
  for (int j = 0; j < 8; ++j) { v0[j] = tile[tc + j][tr]; v1[j] = tile[tc + 8 + j][tr]; }
  bf16* dst = BT + ((size_t)e * DOUT + n0 + tr) * DIN + k0 + tc;
  *(bf16x8*)dst = v0;
  *(bf16x8*)(dst + 8) = v1;
}

// ---------------- pass 2: grouped GEMM, 256x256, 4-slot pipeline ----------------
// C[m][n] = sum_k A[m][k] * BT[e][n][k]
// Staging-BW-bound analysis (r3): 2 GB staged / 64 MB unique. Dispatch order
// makes mtile fastest within an XCD chunk so 4 consecutive CUs share each
// B-panel via L2 and the XCD working set (4 A + 8 B panels) is cache-sized.
#define BM 256
#define BN 256
#define SK 32
#define TPB 512
#define SLOT (2 * BM * SK)   // elems: A[256][32] + B[256][32] = 32 KiB

#define GL(gp, lp) __builtin_amdgcn_global_load_lds(                        \
    (const __attribute__((address_space(1))) void*)(gp),                    \
    (__attribute__((address_space(3))) void*)(lp), 16, 0, 0)

__global__ __launch_bounds__(TPB, 2) void grouped_gemm(
    const bf16* __restrict__ A, const bf16* __restrict__ BT,
    const void* __restrict__ es, float* __restrict__ C) {
  __shared__ bf16 smem[4 * SLOT];   // 128 KiB

  // XCD-chunked, mtile-fastest: chunk c owns mtiles 4c..4c+3 x all ntiles.
  // 4 consecutive blocks on one XCD share a B-panel (L2 reuse).
  const int bid   = blockIdx.x;
  const int c     = bid & 7;
  const int local = bid >> 3;            // 0..127
  const int ntile = local >> 2;          // 0..31
  const int mtile = c * 4 + (local & 3); // 0..31
  const int mrow  = mtile * BM;
  const int ncol  = ntile * BN;

  // expert offsets (int32 or int64 input)
  const int* p32 = (const int*)es;
  const long long* p64 = (const long long*)es;
  const bool is64 = (p32[1] == 0);
  int offs[NE + 1];
  offs[0] = 0;
  #pragma unroll
  for (int i = 0; i < NE; ++i)
    offs[i + 1] = offs[i] + (int)(is64 ? p64[i] : (long long)p32[i]);
  int e0 = 0, e1 = 0;
  #pragma unroll
  for (int i = 0; i < NE; ++i) {
    if (mrow >= offs[i + 1]) e0 = i + 1;
    if (mrow + BM - 1 >= offs[i + 1]) e1 = i + 1;
  }

  const int t    = threadIdx.x;
  const int lane = t & 63;
  const int w    = t >> 6;
  const int wm   = w >> 2;           // 0/1  -> rows wm*128
  const int wn   = w & 3;            // 0..3 -> cols wn*64
  const int l15  = lane & 15;
  const int kg   = lane >> 4;

  // swizzled ds_read col offset (elems), per-lane constant
  const int sw_read = (kg ^ ((l15 >> 1) & 3)) * 8;

  // staging: linear LDS dest, pre-swizzled global source col
  const int srow = t >> 2;                              // 0..127
  const int ssrc = ((t & 3) ^ ((t >> 3) & 3)) * 8;      // elems within SK
  const int sdst = t * 8;                               // elems within chunk

  const bf16* Ag0 = A + (size_t)(mrow + srow) * DIN + ssrc;
  const bf16* Ag1 = Ag0 + (size_t)128 * DIN;
  float* Cb = C + (size_t)mrow * DOUT + ncol;

  for (int e = e0; e <= e1; ++e) {
    const bf16* Bg0 = BT + ((size_t)e * DOUT + ncol + srow) * DIN + ssrc;
    const bf16* Bg1 = Bg0 + (size_t)128 * DIN;

    f32x4 acc[8][4];
    #pragma unroll
    for (int m = 0; m < 8; ++m)
      #pragma unroll
      for (int n = 0; n < 4; ++n) acc[m][n] = (f32x4){0.f, 0.f, 0.f, 0.f};

#define STAGE(ST) do {                                                      \
    const int k0_ = (ST) * SK;                                              \
    bf16* Ld_ = smem + ((ST) & 3) * SLOT + sdst;                            \
    GL(Ag0 + k0_, Ld_);                                                     \
    GL(Ag1 + k0_, Ld_ + 4096);                                              \
    GL(Bg0 + k0_, Ld_ + 8192);                                              \
    GL(Bg1 + k0_, Ld_ + 12288);                                             \
  } while (0)

#define KSTEP(S, DO_STAGE, GATESTR) do {                                    \
    const bf16* Ab_ = smem + ((S) & 3) * SLOT;                              \
    const bf16* Bb_ = Ab_ + BM * SK;                                        \
    if (DO_STAGE) STAGE((S) + 3);                                           \
    bf16x8 aF[8], bF01[2], bF23[2];                                         \
    _Pragma("unroll")                                                       \
    for (int m_ = 0; m_ < 8; ++m_)                                          \
      aF[m_] = *(const bf16x8*)&Ab_[(wm * 128 + m_ * 16 + l15) * SK + sw_read]; \
    _Pragma("unroll")                                                       \
    for (int n_ = 0; n_ < 2; ++n_)                                          \
      bF01[n_] = *(const bf16x8*)&Bb_[(wn * 64 + n_ * 16 + l15) * SK + sw_read]; \
    _Pragma("unroll")                                                       \
    for (int n_ = 0; n_ < 2; ++n_)                                          \
      bF23[n_] = *(const bf16x8*)&Bb_[(wn * 64 + (2 + n_) * 16 + l15) * SK + sw_read]; \
    __builtin_amdgcn_s_setprio(1);                                          \
    _Pragma("unroll")                                                       \
    for (int m_ = 0; m_ < 8; ++m_)                                          \
      _Pragma("unroll")                                                     \
      for (int n_ = 0; n_ < 2; ++n_)                                        \
        acc[m_][n_] = __builtin_amdgcn_mfma_f32_16x16x32_bf16(              \
            aF[m_], bF01[n_], acc[m_][n_], 0, 0, 0);                        \
    _Pragma("unroll")                                                       \
    for (int m_ = 0; m_ < 8; ++m_)                                          \
      _Pragma("unroll")                                                     \
      for (int n_ = 0; n_ < 2; ++n_)                                        \
        acc[m_][2 + n_] = __builtin_amdgcn_mfma_f32_16x16x32_bf16(          \
            aF[m_], bF23[n_], acc[m_][2 + n_], 0, 0, 0);                    \
    __builtin_amdgcn_s_setprio(0);                                          \
    asm volatile("s_waitcnt " GATESTR ::: "memory");                        \
    __builtin_amdgcn_s_barrier();                                           \
    __builtin_amdgcn_sched_barrier(0);                                      \
  } while (0)

    // prologue: stage steps 0,1,2 -> slots 0,1,2 (12 gloads/thread)
    STAGE(0); STAGE(1); STAGE(2);
    asm volatile("s_waitcnt vmcnt(8)" ::: "memory");  // step 0 landed
    __builtin_amdgcn_s_barrier();
    __builtin_amdgcn_sched_barrier(0);

    // main loop: 64 steps of K=32; stage s+3 while computing s
    for (int s = 0; s < 61; ++s) KSTEP(s, true, "vmcnt(8)");
    KSTEP(61, false, "vmcnt(4)");
    KSTEP(62, false, "vmcnt(0)");
    KSTEP(63, false, "vmcnt(0)");

#undef KSTEP
#undef STAGE

    // ---- epilogue: masked C-write (mask matters only for split tiles)
    int rlo = offs[e] - mrow;     if (rlo < 0)  rlo = 0;
    int rhi = offs[e + 1] - mrow; if (rhi > BM) rhi = BM;
    #pragma unroll
    for (int m = 0; m < 8; ++m) {
      const int rb = wm * 128 + m * 16 + kg * 4;
      #pragma unroll
      for (int j = 0; j < 4; ++j) {
        const int r = rb + j;
        if (r >= rlo && r < rhi) {
          #pragma unroll
          for (int n = 0; n < 4; ++n)
            Cb[(size_t)r * DOUT + wn * 64 + n * 16 + l15] = acc[m][n][j];
        }
      }
    }
  }
}

// ---------------- fallback (ws too small): fp32 tiled GEMM ----------------
__device__ __forceinline__ int find_expert_fb(const void* esv, int mrow) {
  const int* p32 = (const int*)esv;
  const long long* p64 = (const long long*)esv;
  bool is64 = (p32[1] == 0);
  long long cum = 0; int e = 0;
  #pragma unroll
  for (int i = 0; i < NE; ++i) {
    long long s = is64 ? p64[i] : (long long)p32[i];
    long long nx = cum + s;
    if ((long long)mrow >= nx) e = i + 1;
    cum = nx;
  }
  return e;
}

__global__ __launch_bounds__(256) void fallback_gemm(
    const float* __restrict__ A, const float* __restrict__ W,
    const void* __restrict__ es, float* __restrict__ C) {
  __shared__ float As[64][17];
  __shared__ float Bs[16][65];
  const int bid = blockIdx.x;
  const int mtile = bid >> 7;
  const int ntile = bid & 127;
  const int mrow = mtile * 64, ncol = ntile * 64;
  const int e = find_expert_fb(es, mrow);
  const int t = threadIdx.x;
  const int tx = t & 15, ty = t >> 4;
  float acc[4][4] = {};
  const float* Ab = A + (size_t)mrow * DIN;
  const float* Wb = W + (size_t)e * DIN * DOUT + ncol;
  for (int kb = 0; kb < DIN; kb += 16) {
    {
      const int r = t >> 2, c = (t & 3) * 4;
      float4 v = *(const float4*)(Ab + (size_t)r * DIN + kb + c);
      const float* f = (const float*)&v;
      #pragma unroll
      for (int j = 0; j < 4; ++j) As[r][c + j] = f[j];
      const int r2 = t >> 4, c2 = (t & 15) * 4;
      float4 wv = *(const float4*)(Wb + (size_t)(kb + r2) * DOUT + c2);
      const float* g = (const float*)&wv;
      #pragma unroll
      for (int j = 0; j < 4; ++j) Bs[r2][c2 + j] = g[j];
    }
    __syncthreads();
    #pragma unroll
    for (int k = 0; k < 16; ++k)
      #pragma unroll
      for (int i = 0; i < 4; ++i)
        #pragma unroll
        for (int j = 0; j < 4; ++j)
          acc[i][j] += As[ty * 4 + i][k] * Bs[k][tx * 4 + j];
    __syncthreads();
  }
  #pragma unroll
  for (int i = 0; i < 4; ++i)
    #pragma unroll
    for (int j = 0; j < 4; ++j)
      C[(size_t)(mrow + ty * 4 + i) * DOUT + ncol + tx * 4 + j] = acc[i][j];
}

extern "C" void kernel_launch(void* const* d_in, const int* in_sizes, int n_in,
                              void* d_out, int out_size, void* d_ws, size_t ws_size,
                              hipStream_t stream) {
  const float* A = (const float*)d_in[0];
  const float* W = (const float*)d_in[1];
  const void*  es = (const void*)d_in[2];
  float* C = (float*)d_out;

  const size_t needA = (size_t)NTOK * DIN * sizeof(bf16);        // 32 MB
  const size_t needB = (size_t)NE * DIN * DOUT * sizeof(bf16);   // 256 MB

  if (ws_size >= needA + needB) {
    bf16* Ab = (bf16*)d_ws;
    bf16* BT = (bf16*)((char*)d_ws + needA);
    convertA<<<(NTOK * DIN) / (256 * 8), 256, 0, stream>>>(A, Ab);
    dim3 gB(DOUT / 64, DIN / 64, NE);
    convertB<<<gB, 256, 0, stream>>>(W, BT);
    grouped_gemm<<<(NTOK / BM) * (DOUT / BN), TPB, 0, stream>>>(Ab, BT, es, C);
  } else {
    fallback_gemm<<<(NTOK / 64) * (DOUT / 64), 256, 0, stream>>>(A, W, es, C);
  }
}

// Round 5
// 567.381 us; speedup vs baseline: 1.3138x; 1.3138x over previous
//
#include <hip/hip_runtime.h>
#include <hip/hip_bf16.h>

#define NE   8
#define DIN  2048
#define DOUT 8192
#define NTOK 8192

typedef __bf16 bf16;
typedef __attribute__((ext_vector_type(8))) __bf16 bf16x8;
typedef __attribute__((ext_vector_type(4))) float f32x4;

// round-to-nearest-even f32 -> bf16 (finite inputs)
__device__ __forceinline__ bf16 f2bf(float x) {
  union { float f; unsigned u; } v; v.f = x;
  unsigned r = v.u + 0x7fffu + ((v.u >> 16) & 1u);
  union { unsigned short s; bf16 b; } o; o.s = (unsigned short)(r >> 16);
  return o.b;
}

__device__ __forceinline__ int find_expert(const void* esv, int mrow) {
  const int* p32 = (const int*)esv;
  const long long* p64 = (const long long*)esv;
  bool is64 = (p32[1] == 0);
  long long cum = 0; int e = 0;
  #pragma unroll
  for (int i = 0; i < NE; ++i) {
    long long s = is64 ? p64[i] : (long long)p32[i];
    long long nx = cum + s;
    if ((long long)mrow >= nx) e = i + 1;
    cum = nx;
  }
  return e;
}

// ---------------- pass 1a: A fp32 -> bf16 (same layout) ----------------
__global__ __launch_bounds__(256) void convertA(const float* __restrict__ A,
                                                bf16* __restrict__ Ab) {
  size_t i = ((size_t)blockIdx.x * 256 + threadIdx.x) * 8;
  float4 a = *(const float4*)(A + i);
  float4 b = *(const float4*)(A + i + 4);
  const float* f = (const float*)&a;
  const float* g = (const float*)&b;
  bf16x8 v;
  #pragma unroll
  for (int j = 0; j < 4; ++j) { v[j] = f2bf(f[j]); v[4 + j] = f2bf(g[j]); }
  *(bf16x8*)(Ab + i) = v;
}

// ------- pass 1b: W [E][K][N] fp32 -> BT [E][N][K] bf16 (transpose) -------
__global__ __launch_bounds__(256) void convertB(const float* __restrict__ W,
                                                bf16* __restrict__ BT) {
  __shared__ bf16 tile[64][66];
  const int e  = blockIdx.z;
  const int n0 = blockIdx.x * 64;
  const int k0 = blockIdx.y * 64;
  const int t  = threadIdx.x;
  const int tr = t >> 2;
  const int tc = (t & 3) << 4;

  const float* src = W + ((size_t)e * DIN + k0 + tr) * DOUT + n0 + tc;
  #pragma unroll
  for (int i = 0; i < 4; ++i) {
    float4 v = *(const float4*)(src + 4 * i);
    const float* f = (const float*)&v;
    #pragma unroll
    for (int j = 0; j < 4; ++j) tile[tr][tc + 4 * i + j] = f2bf(f[j]);
  }
  __syncthreads();

  bf16x8 v0, v1;
  #pragma unroll
  for (int j = 0; j < 8; ++j) { v0[j] = tile[tc + j][tr]; v1[j] = tile[tc + 8 + j][tr]; }
  bf16* dst = BT + ((size_t)e * DOUT + n0 + tr) * DIN + k0 + tc;
  *(bf16x8*)dst = v0;
  *(bf16x8*)(dst + 8) = v1;
}

// ------------- pass 2: grouped GEMM, m97 structure + XOR swizzle -------------
// C[m][n] = sum_k A[m][k] * BT[e][n][k]. 128x128 tile, BK=64, 4 waves,
// 32 KiB LDS (~3 blocks/CU -> implicit cross-block overlap, m114).
// Bank-conflict fix (r1 had 1e8, 16-way): granule swizzle g' = g ^ (row&7),
// applied on BOTH sides (rule 21): linear gload_lds dest + pre-swizzled
// GLOBAL source col + swizzled ds_read col. 16 frag lanes -> 2-way = free.
// Expert boundaries are all multiples of 128 -> tiles never split experts.
#define BM 128
#define BN 128
#define BK 64

#define GL(gp, lp) __builtin_amdgcn_global_load_lds(                        \
    (const __attribute__((address_space(1))) void*)(gp),                    \
    (__attribute__((address_space(3))) void*)(lp), 16, 0, 0)

__global__ __launch_bounds__(256) void grouped_gemm(
    const bf16* __restrict__ A, const bf16* __restrict__ BT,
    const void* __restrict__ es, float* __restrict__ C) {
  __shared__ bf16 As[BM * BK];
  __shared__ bf16 Bs[BN * BK];

  // XCD-chunked (4096 % 8 == 0): chunk c = 8 mtiles x 64 ntiles, ntile-fastest
  const int bid   = blockIdx.x;
  const int wid   = (bid & 7) * 512 + (bid >> 3);
  const int mtile = wid >> 6;
  const int ntile = wid & 63;
  const int mrow  = mtile * BM;
  const int ncol  = ntile * BN;
  const int e     = find_expert(es, mrow);

  const int t    = threadIdx.x;
  const int lane = t & 63;
  const int wr   = ((t >> 6) >> 1) * 64;   // wave rows: 0/64
  const int wc   = ((t >> 6) & 1) * 64;    // wave cols: 0/64
  const int l15  = lane & 15;
  const int kg   = lane >> 4;              // 0..3

  // staging: thread t owns LDS row i*32 + (t>>3), granule t&7 (dest linear
  // in t); source col pre-swizzled so read-side XOR recovers global col
  const int srow = t >> 3;                              // 0..31
  const int ssrc = ((t & 7) ^ ((t >> 3) & 7)) * 8;      // elems
  const int sdst = t * 8;                               // elems per 32-row chunk

  const bf16* Ag = A + (size_t)(mrow + srow) * DIN + ssrc;
  const bf16* Bg = BT + ((size_t)e * DOUT + ncol + srow) * DIN + ssrc;

  f32x4 acc[4][4];
  #pragma unroll
  for (int m = 0; m < 4; ++m)
    #pragma unroll
    for (int n = 0; n < 4; ++n) acc[m][n] = (f32x4){0.f, 0.f, 0.f, 0.f};

  // swizzled read cols for kk = 0,1 (per-lane constants)
  const int rc0 = ((0 * 4 + kg) ^ (l15 & 7)) * 8;
  const int rc1 = ((1 * 4 + kg) ^ (l15 & 7)) * 8;

  for (int kt = 0; kt < DIN / BK; ++kt) {
    const int kb = kt * BK;
    #pragma unroll
    for (int i = 0; i < 4; ++i) {
      GL(Ag + (size_t)(i * 32) * DIN + kb, As + i * 2048 + sdst);
      GL(Bg + (size_t)(i * 32) * DIN + kb, Bs + i * 2048 + sdst);
    }
    __syncthreads();   // compiler drains vmcnt before s_barrier

    #pragma unroll
    for (int kk = 0; kk < 2; ++kk) {
      const int rc = kk ? rc1 : rc0;
      bf16x8 af[4], bfr[4];
      #pragma unroll
      for (int m = 0; m < 4; ++m)
        af[m] = *(const bf16x8*)&As[(wr + m * 16 + l15) * BK + rc];
      #pragma unroll
      for (int n = 0; n < 4; ++n)
        bfr[n] = *(const bf16x8*)&Bs[(wc + n * 16 + l15) * BK + rc];
      #pragma unroll
      for (int m = 0; m < 4; ++m)
        #pragma unroll
        for (int n = 0; n < 4; ++n)
          acc[m][n] = __builtin_amdgcn_mfma_f32_16x16x32_bf16(
              af[m], bfr[n], acc[m][n], 0, 0, 0);
    }
    __syncthreads();
  }

  // C/D layout: col = lane&15, row = (lane>>4)*4 + reg
  float* Cb = C + (size_t)mrow * DOUT + ncol;
  const int r0 = wr + kg * 4;
  const int c0 = wc + l15;
  #pragma unroll
  for (int m = 0; m < 4; ++m)
    #pragma unroll
    for (int j = 0; j < 4; ++j)
      #pragma unroll
      for (int n = 0; n < 4; ++n)
        Cb[(size_t)(r0 + m * 16 + j) * DOUT + c0 + n * 16] = acc[m][n][j];
}

// ---------------- fallback (ws too small): fp32 tiled GEMM ----------------
__global__ __launch_bounds__(256) void fallback_gemm(
    const float* __restrict__ A, const float* __restrict__ W,
    const void* __restrict__ es, float* __restrict__ C) {
  __shared__ float Asf[64][17];
  __shared__ float Bsf[16][65];
  const int bid = blockIdx.x;
  const int mtile = bid >> 7;
  const int ntile = bid & 127;
  const int mrow = mtile * 64, ncol = ntile * 64;
  const int e = find_expert(es, mrow);
  const int t = threadIdx.x;
  const int tx = t & 15, ty = t >> 4;
  float acc[4][4] = {};
  const float* Ab = A + (size_t)mrow * DIN;
  const float* Wb = W + (size_t)e * DIN * DOUT + ncol;
  for (int kb = 0; kb < DIN; kb += 16) {
    {
      const int r = t >> 2, c = (t & 3) * 4;
      float4 v = *(const float4*)(Ab + (size_t)r * DIN + kb + c);
      const float* f = (const float*)&v;
      #pragma unroll
      for (int j = 0; j < 4; ++j) Asf[r][c + j] = f[j];
      const int r2 = t >> 4, c2 = (t & 15) * 4;
      float4 wv = *(const float4*)(Wb + (size_t)(kb + r2) * DOUT + c2);
      const float* g = (const float*)&wv;
      #pragma unroll
      for (int j = 0; j < 4; ++j) Bsf[r2][c2 + j] = g[j];
    }
    __syncthreads();
    #pragma unroll
    for (int k = 0; k < 16; ++k)
      #pragma unroll
      for (int i = 0; i < 4; ++i)
        #pragma unroll
        for (int j = 0; j < 4; ++j)
          acc[i][j] += Asf[ty * 4 + i][k] * Bsf[k][tx * 4 + j];
    __syncthreads();
  }
  #pragma unroll
  for (int i = 0; i < 4; ++i)
    #pragma unroll
    for (int j = 0; j < 4; ++j)
      C[(size_t)(mrow + ty * 4 + i) * DOUT + ncol + tx * 4 + j] = acc[i][j];
}

extern "C" void kernel_launch(void* const* d_in, const int* in_sizes, int n_in,
                              void* d_out, int out_size, void* d_ws, size_t ws_size,
                              hipStream_t stream) {
  const float* A = (const float*)d_in[0];
  const float* W = (const float*)d_in[1];
  const void*  es = (const void*)d_in[2];
  float* C = (float*)d_out;

  const size_t needA = (size_t)NTOK * DIN * sizeof(bf16);        // 32 MB
  const size_t needB = (size_t)NE * DIN * DOUT * sizeof(bf16);   // 256 MB

  if (ws_size >= needA + needB) {
    bf16* Ab = (bf16*)d_ws;
    bf16* BT = (bf16*)((char*)d_ws + needA);
    convertA<<<(NTOK * DIN) / (256 * 8), 256, 0, stream>>>(A, Ab);
    dim3 gB(DOUT / 64, DIN / 64, NE);
    convertB<<<gB, 256, 0, stream>>>(W, BT);
    grouped_gemm<<<(NTOK / BM) * (DOUT / BN), 256, 0, stream>>>(Ab, BT, es, C);
  } else {
    fallback_gemm<<<(NTOK / 64) * (DOUT / 64), 256, 0, stream>>>(A, W, es, C);
  }
}

// Round 6
// 508.262 us; speedup vs baseline: 1.4667x; 1.1163x over previous
//
#include <hip/hip_runtime.h>
#include <hip/hip_bf16.h>

#define NE   8
#define DIN  2048
#define DOUT 8192
#define NTOK 8192

typedef __bf16 bf16;
typedef __attribute__((ext_vector_type(8))) __bf16 bf16x8;
typedef __attribute__((ext_vector_type(4))) float f32x4;

// round-to-nearest-even f32 -> bf16 (finite inputs)
__device__ __forceinline__ bf16 f2bf(float x) {
  union { float f; unsigned u; } v; v.f = x;
  unsigned r = v.u + 0x7fffu + ((v.u >> 16) & 1u);
  union { unsigned short s; bf16 b; } o; o.s = (unsigned short)(r >> 16);
  return o.b;
}

__device__ __forceinline__ int find_expert(const void* esv, int mrow) {
  const int* p32 = (const int*)esv;
  const long long* p64 = (const long long*)esv;
  bool is64 = (p32[1] == 0);
  long long cum = 0; int e = 0;
  #pragma unroll
  for (int i = 0; i < NE; ++i) {
    long long s = is64 ? p64[i] : (long long)p32[i];
    long long nx = cum + s;
    if ((long long)mrow >= nx) e = i + 1;
    cum = nx;
  }
  return e;
}

// ---------------- pass 1a: A fp32 -> bf16 (same layout) ----------------
__global__ __launch_bounds__(256) void convertA(const float* __restrict__ A,
                                                bf16* __restrict__ Ab) {
  size_t i = ((size_t)blockIdx.x * 256 + threadIdx.x) * 8;
  float4 a = *(const float4*)(A + i);
  float4 b = *(const float4*)(A + i + 4);
  const float* f = (const float*)&a;
  const float* g = (const float*)&b;
  bf16x8 v;
  #pragma unroll
  for (int j = 0; j < 4; ++j) { v[j] = f2bf(f[j]); v[4 + j] = f2bf(g[j]); }
  *(bf16x8*)(Ab + i) = v;
}

// ------- pass 1b: W [E][K][N] fp32 -> BT [E][N][K] bf16 (transpose) -------
__global__ __launch_bounds__(256) void convertB(const float* __restrict__ W,
                                                bf16* __restrict__ BT) {
  __shared__ bf16 tile[64][66];
  const int e  = blockIdx.z;
  const int n0 = blockIdx.x * 64;
  const int k0 = blockIdx.y * 64;
  const int t  = threadIdx.x;
  const int tr = t >> 2;
  const int tc = (t & 3) << 4;

  const float* src = W + ((size_t)e * DIN + k0 + tr) * DOUT + n0 + tc;
  #pragma unroll
  for (int i = 0; i < 4; ++i) {
    float4 v = *(const float4*)(src + 4 * i);
    const float* f = (const float*)&v;
    #pragma unroll
    for (int j = 0; j < 4; ++j) tile[tr][tc + 4 * i + j] = f2bf(f[j]);
  }
  __syncthreads();

  bf16x8 v0, v1;
  #pragma unroll
  for (int j = 0; j < 8; ++j) { v0[j] = tile[tc + j][tr]; v1[j] = tile[tc + 8 + j][tr]; }
  bf16* dst = BT + ((size_t)e * DOUT + n0 + tr) * DIN + k0 + tc;
  *(bf16x8*)dst = v0;
  *(bf16x8*)(dst + 8) = v1;
}

// ------------- pass 2: grouped GEMM, m97 structure + XOR swizzle -------------
// C[m][n] = sum_k A[m][k] * BT[e][n][k]. 128x128 tile, BK=64, 4 waves,
// 32 KiB LDS (~2.5 blocks/CU -> implicit cross-block overlap, m114).
// Swizzle (verified r5, conflicts=0): granule g' = g ^ (row&7), both sides.
// L2-coop order (r6): XCD c owns ntiles [8c,8c+8) x all 64 mtiles ->
// each B-panel fetched by exactly one XCD; per-expert 4 MB B-slice stays
// L2-resident across that expert's mtiles; A (32 MB) L3-resident.
#define BM 128
#define BN 128
#define BK 64

#define GL(gp, lp) __builtin_amdgcn_global_load_lds(                        \
    (const __attribute__((address_space(1))) void*)(gp),                    \
    (__attribute__((address_space(3))) void*)(lp), 16, 0, 0)

__global__ __launch_bounds__(256) void grouped_gemm(
    const bf16* __restrict__ A, const bf16* __restrict__ BT,
    const void* __restrict__ es, float* __restrict__ C) {
  __shared__ bf16 As[BM * BK];
  __shared__ bf16 Bs[BN * BK];

  // XCD ntile-slice dispatch: c = XCD, ntile = c*8 + (local&7), mtile = local>>3
  const int bid   = blockIdx.x;
  const int c     = bid & 7;
  const int local = bid >> 3;            // 0..511
  const int mtile = local >> 3;          // 0..63  (ntile-fastest: share A-panel)
  const int ntile = c * 8 + (local & 7); // 0..63
  const int mrow  = mtile * BM;
  const int ncol  = ntile * BN;
  const int e     = find_expert(es, mrow);

  const int t    = threadIdx.x;
  const int lane = t & 63;
  const int wr   = ((t >> 6) >> 1) * 64;   // wave rows: 0/64
  const int wc   = ((t >> 6) & 1) * 64;    // wave cols: 0/64
  const int l15  = lane & 15;
  const int kg   = lane >> 4;              // 0..3

  // staging: linear LDS dest (t*16B), pre-swizzled global source col
  const int srow = t >> 3;                              // 0..31
  const int ssrc = ((t & 7) ^ ((t >> 3) & 7)) * 8;      // elems
  const int sdst = t * 8;                               // elems per 32-row chunk

  const bf16* Ag = A + (size_t)(mrow + srow) * DIN + ssrc;
  const bf16* Bg = BT + ((size_t)e * DOUT + ncol + srow) * DIN + ssrc;

  f32x4 acc[4][4];
  #pragma unroll
  for (int m = 0; m < 4; ++m)
    #pragma unroll
    for (int n = 0; n < 4; ++n) acc[m][n] = (f32x4){0.f, 0.f, 0.f, 0.f};

  // swizzled read cols for kk = 0,1 (per-lane constants)
  const int rc0 = ((0 * 4 + kg) ^ (l15 & 7)) * 8;
  const int rc1 = ((1 * 4 + kg) ^ (l15 & 7)) * 8;

  for (int kt = 0; kt < DIN / BK; ++kt) {
    const int kb = kt * BK;
    #pragma unroll
    for (int i = 0; i < 4; ++i) {
      GL(Ag + (size_t)(i * 32) * DIN + kb, As + i * 2048 + sdst);
      GL(Bg + (size_t)(i * 32) * DIN + kb, Bs + i * 2048 + sdst);
    }
    __syncthreads();   // compiler drains vmcnt before s_barrier

    #pragma unroll
    for (int kk = 0; kk < 2; ++kk) {
      const int rc = kk ? rc1 : rc0;
      bf16x8 af[4], bfr[4];
      #pragma unroll
      for (int m = 0; m < 4; ++m)
        af[m] = *(const bf16x8*)&As[(wr + m * 16 + l15) * BK + rc];
      #pragma unroll
      for (int n = 0; n < 4; ++n)
        bfr[n] = *(const bf16x8*)&Bs[(wc + n * 16 + l15) * BK + rc];
      #pragma unroll
      for (int m = 0; m < 4; ++m)
        #pragma unroll
        for (int n = 0; n < 4; ++n)
          acc[m][n] = __builtin_amdgcn_mfma_f32_16x16x32_bf16(
              af[m], bfr[n], acc[m][n], 0, 0, 0);
    }
    __syncthreads();
  }

  // C/D layout: col = lane&15, row = (lane>>4)*4 + reg
  float* Cb = C + (size_t)mrow * DOUT + ncol;
  const int r0 = wr + kg * 4;
  const int c0 = wc + l15;
  #pragma unroll
  for (int m = 0; m < 4; ++m)
    #pragma unroll
    for (int j = 0; j < 4; ++j)
      #pragma unroll
      for (int n = 0; n < 4; ++n)
        Cb[(size_t)(r0 + m * 16 + j) * DOUT + c0 + n * 16] = acc[m][n][j];
}

// ---------------- fallback (ws too small): fp32 tiled GEMM ----------------
__global__ __launch_bounds__(256) void fallback_gemm(
    const float* __restrict__ A, const float* __restrict__ W,
    const void* __restrict__ es, float* __restrict__ C) {
  __shared__ float Asf[64][17];
  __shared__ float Bsf[16][65];
  const int bid = blockIdx.x;
  const int mtile = bid >> 7;
  const int ntile = bid & 127;
  const int mrow = mtile * 64, ncol = ntile * 64;
  const int e = find_expert(es, mrow);
  const int t = threadIdx.x;
  const int tx = t & 15, ty = t >> 4;
  float acc[4][4] = {};
  const float* Ab = A + (size_t)mrow * DIN;
  const float* Wb = W + (size_t)e * DIN * DOUT + ncol;
  for (int kb = 0; kb < DIN; kb += 16) {
    {
      const int r = t >> 2, c = (t & 3) * 4;
      float4 v = *(const float4*)(Ab + (size_t)r * DIN + kb + c);
      const float* f = (const float*)&v;
      #pragma unroll
      for (int j = 0; j < 4; ++j) Asf[r][c + j] = f[j];
      const int r2 = t >> 4, c2 = (t & 15) * 4;
      float4 wv = *(const float4*)(Wb + (size_t)(kb + r2) * DOUT + c2);
      const float* g = (const float*)&wv;
      #pragma unroll
      for (int j = 0; j < 4; ++j) Bsf[r2][c2 + j] = g[j];
    }
    __syncthreads();
    #pragma unroll
    for (int k = 0; k < 16; ++k)
      #pragma unroll
      for (int i = 0; i < 4; ++i)
        #pragma unroll
        for (int j = 0; j < 4; ++j)
          acc[i][j] += Asf[ty * 4 + i][k] * Bsf[k][tx * 4 + j];
    __syncthreads();
  }
  #pragma unroll
  for (int i = 0; i < 4; ++i)
    #pragma unroll
    for (int j = 0; j < 4; ++j)
      C[(size_t)(mrow + ty * 4 + i) * DOUT + ncol + tx * 4 + j] = acc[i][j];
}

extern "C" void kernel_launch(void* const* d_in, const int* in_sizes, int n_in,
                              void* d_out, int out_size, void* d_ws, size_t ws_size,
                              hipStream_t stream) {
  const float* A = (const float*)d_in[0];
  const float* W = (const float*)d_in[1];
  const void*  es = (const void*)d_in[2];
  float* C = (float*)d_out;

  const size_t needA = (size_t)NTOK * DIN * sizeof(bf16);        // 32 MB
  const size_t needB = (size_t)NE * DIN * DOUT * sizeof(bf16);   // 256 MB

  if (ws_size >= needA + needB) {
    bf16* Ab = (bf16*)d_ws;
    bf16* BT = (bf16*)((char*)d_ws + needA);
    convertA<<<(NTOK * DIN) / (256 * 8), 256, 0, stream>>>(A, Ab);
    dim3 gB(DOUT / 64, DIN / 64, NE);
    convertB<<<gB, 256, 0, stream>>>(W, BT);
    grouped_gemm<<<(NTOK / BM) * (DOUT / BN), 256, 0, stream>>>(Ab, BT, es, C);
  } else {
    fallback_gemm<<<(NTOK / 64) * (DOUT / 64), 256, 0, stream>>>(A, W, es, C);
  }
}